// Round 7
// baseline (2029.718 us; speedup 1.0000x reference)
//
#include <hip/hip_runtime.h>
#include <math.h>

#define NTHREADS 1024

namespace {
constexpr int kB = 8, kS = 96, kIN = 128, kH = 2, kM = 32, kN = 512;
constexpr int kSTATE = 256, kOUT = 126, kUH = 106;
constexpr int kNC = 594;            // GEMV output columns (256+126+212)
constexpr int kKR = 320;            // recurrent GEMV rows (read 64 + state 256)
constexpr int kRP = 160;            // row-pairs
constexpr int kREG = 64;            // row-pairs held in registers
constexpr int kMLD = 520;           // padded mem row stride
constexpr float kEPS = 1e-12f;
constexpr int kXWfloats = kB * kS * kNC;
constexpr size_t kWbOffBytes = (size_t)kXWfloats * 4;
}

__device__ __forceinline__ float sigm_(float x) { return 1.0f / (1.0f + __expf(-x)); }
__device__ __forceinline__ float splus_(float x) { return x > 20.0f ? x : __logf(1.0f + __expf(x)); }
__device__ __forceinline__ float blo_(unsigned int u) { return __uint_as_float(u << 16); }
__device__ __forceinline__ float bhi_(unsigned int u) { return __uint_as_float(u & 0xffff0000u); }

// ---- prep A: xw[row][c] = bias[c] + sum_{i<128} x[row][i] * W[i][c] ----
__global__ __launch_bounds__(640) void prep_xw(
    const float* __restrict__ x,
    const float* __restrict__ Ws, const float* __restrict__ bs,
    const float* __restrict__ Wo, const float* __restrict__ bo,
    const float* __restrict__ Wu, const float* __restrict__ bu,
    float* __restrict__ xw)
{
    __shared__ float sx[kIN];
    const int row = blockIdx.x;
    const int t = threadIdx.x;
    if (t < kIN) sx[t] = x[row * kIN + t];
    __syncthreads();
    if (t < kNC) {
        const float* Wp; int ld, j; float acc;
        if (t < 256)      { Wp = Ws; ld = kSTATE;   j = t;       acc = bs[j]; }
        else if (t < 382) { Wp = Wo; ld = kOUT;     j = t - 256; acc = bo[j]; }
        else              { Wp = Wu; ld = kH * kUH; j = t - 382; acc = bu[j]; }
        const float* p = Wp + j;
        #pragma unroll 8
        for (int i = 0; i < kIN; ++i) acc = fmaf(sx[i], p[i * ld], acc);
        xw[row * kNC + t] = acc;
    }
}

__device__ __forceinline__ unsigned short rtn_bf16_(float v) {
    unsigned int bits = __float_as_uint(v);
    return (unsigned short)((bits + 0x7fffu + ((bits >> 16) & 1u)) >> 16);
}

// ---- prep B: Wb[r][c] = pack(bf16(w[2r][c]), bf16(w[2r+1][c])), rows = recurrent rows ----
__global__ __launch_bounds__(1024) void prep_pack(
    const float* __restrict__ Ws, const float* __restrict__ Wo,
    const float* __restrict__ Wu, unsigned int* __restrict__ Wb)
{
    int idx = blockIdx.x * 1024 + threadIdx.x;
    if (idx >= kRP * kNC) return;
    int r = idx / kNC, c = idx - r * kNC;
    auto fetch = [&](int i) -> float {
        int row = kIN + i;
        if (c < 256)      return Ws[row * kSTATE + c];
        else if (c < 382) return Wo[row * kOUT + (c - 256)];
        else              return Wu[row * (kH * kUH) + (c - 382)];
    };
    unsigned int lo = rtn_bf16_(fetch(2 * r));
    unsigned int hi = rtn_bf16_(fetch(2 * r + 1));
    Wb[idx] = (hi << 16) | lo;
}

__global__ __launch_bounds__(NTHREADS) void dwm_kernel(
    const float* __restrict__ xw,
    const unsigned int* __restrict__ Wb,   // [160][594] row-pair packed bf16
    float* __restrict__ out)
{
    __shared__ float s_mem[kM * kMLD];     // 66.6 KB memory [M][N] (padded)
    __shared__ float s_wt[kH * kN];
    __shared__ float s_wtd[kH * kN];
    __shared__ float s_tmp[kH * kN];
    __shared__ float s_comb[kKR];          // [read(64) | state(256)]
    __shared__ float s_upd[kH * kUH];      // scalar interface params (raw)
    __shared__ float s_er[kH * kM], s_ad[kH * kM], s_kk[kH * kM];
    __shared__ float s_red[16];
    __shared__ float s_shift[kH][3], s_jmp[kH][3];
    __shared__ float s_jd[kH], s_gam[kH], s_beta[kH], s_g[kH], s_ikn[kH];

    const int b = blockIdx.x;
    const int t = threadIdx.x;
    const int wid = t >> 6;
    const int lane = t & 63;

    // ---- register-resident weight block: first kREG row-pairs for this column ----
    unsigned int wr[kREG];
    const unsigned int* wp = Wb + t;
    if (t < kNC) {
        #pragma unroll
        for (int r = 0; r < kREG; ++r) wr[r] = wp[r * kNC];
    }

    // ---- initial carry ----
    for (int i = t; i < kM * kN; i += NTHREADS)
        s_mem[(i >> 9) * kMLD + (i & 511)] = 0.01f;
    for (int i = t; i < kH * kN; i += NTHREADS) {
        float v = ((i & 511) == 0) ? 1.0f : 0.0f;
        s_wt[i] = v; s_wtd[i] = v;
    }
    if (t < kSTATE) s_comb[64 + t] = 1.0f;   // state0 = 1
    __syncthreads();

    for (int step = 0; step < kS; ++step) {
        // ---- P0: read[h,m] = sum_n wt[h,n]*mem[m,n] via float4 ----
        {
            int g = t >> 4, l16 = t & 15, h = g >> 5, m = g & 31;
            const float4* w4 = (const float4*)&s_wt[h * kN];
            const float4* m4 = (const float4*)&s_mem[m * kMLD];
            float ax = 0.0f, ay = 0.0f, az = 0.0f, aw = 0.0f;
            #pragma unroll
            for (int k = 0; k < 8; ++k) {
                float4 w = w4[l16 + 16 * k];
                float4 mv = m4[l16 + 16 * k];
                ax = fmaf(w.x, mv.x, ax); ay = fmaf(w.y, mv.y, ay);
                az = fmaf(w.z, mv.z, az); aw = fmaf(w.w, mv.w, aw);
            }
            float acc = (ax + ay) + (az + aw);
            acc += __shfl_xor(acc, 1);
            acc += __shfl_xor(acc, 2);
            acc += __shfl_xor(acc, 4);
            acc += __shfl_xor(acc, 8);
            if (l16 == 0) s_comb[g] = acc;
        }
        __syncthreads();

        // ---- P1a: GEMV — thread t owns column t; reg rows + streamed rows ----
        float acc = 0.0f;
        if (t < kNC) {
            acc = xw[(b * kS + step) * kNC + t];
            #pragma unroll
            for (int r = 0; r < kREG; ++r) {
                float2 cc = *(const float2*)&s_comb[2 * r];
                acc = fmaf(blo_(wr[r]), cc.x, acc);
                acc = fmaf(bhi_(wr[r]), cc.y, acc);
            }
            #pragma unroll 16
            for (int r = kREG; r < kRP; ++r) {
                unsigned int u = wp[r * kNC];
                float2 cc = *(const float2*)&s_comb[2 * r];
                acc = fmaf(blo_(u), cc.x, acc);
                acc = fmaf(bhi_(u), cc.y, acc);
            }
        }
        __syncthreads();   // all s_comb reads done before state overwrite

        // ---- P1b: dispatch (activations fused) ----
        if (t < kNC) {
            if (t < kSTATE) {
                s_comb[64 + t] = sigm_(acc);         // next state -> comb slot
            } else if (t < kSTATE + kOUT) {
                out[(b * kS + step) * kOUT + (t - kSTATE)] = acc;
            } else {
                int idx = t - 382;
                int h = idx >= kUH;
                int j = idx - (h ? kUH : 0);
                if (j >= 8 && j < 40)        s_er[h * kM + j - 8]  = sigm_(acc);
                else if (j >= 40 && j < 72)  s_ad[h * kM + j - 40] = acc;
                else if (j >= 72 && j < 104) s_kk[h * kM + j - 72] = tanhf(acc);
                else s_upd[idx] = acc;
            }
        }
        __syncthreads();

        // ---- P2 (t<66) + P3 (all threads) merged ----
        if (t < 64) {
            int h = t >> 5, m = t & 31;
            float kv = s_kk[t];
            float ss = kv * kv;
            ss += __shfl_xor(ss, 1);
            ss += __shfl_xor(ss, 2);
            ss += __shfl_xor(ss, 4);
            ss += __shfl_xor(ss, 8);
            ss += __shfl_xor(ss, 16);
            if (m == 0) s_ikn[h] = 1.0f / (sqrtf(ss) + kEPS);
        } else if (t == 64 || t == 65) {
            int h = t - 64;
            const float* u = &s_upd[h * kUH];
            float b0 = splus_(u[0]), b1 = splus_(u[1]), b2 = splus_(u[2]);
            float mx = fmaxf(b0, fmaxf(b1, b2));
            float e0 = __expf(b0 - mx), e1 = __expf(b1 - mx), e2 = __expf(b2 - mx);
            float inv = 1.0f / (e0 + e1 + e2);
            s_shift[h][0] = e0 * inv; s_shift[h][1] = e1 * inv; s_shift[h][2] = e2 * inv;
            s_jd[h] = sigm_(u[3]);
            b0 = u[4]; b1 = u[5]; b2 = u[6];
            mx = fmaxf(b0, fmaxf(b1, b2));
            e0 = __expf(b0 - mx); e1 = __expf(b1 - mx); e2 = __expf(b2 - mx);
            inv = 1.0f / (e0 + e1 + e2);
            s_jmp[h][0] = e0 * inv; s_jmp[h][1] = e1 * inv; s_jmp[h][2] = e2 * inv;
            s_gam[h]  = 1.0f + splus_(u[7]);
            s_beta[h] = splus_(u[104]);
            s_g[h]    = sigm_(u[105]);
        }
        // P3: erase+add, float4, wt hoisted (uses OLD s_wt)
        {
            int tn = t & 127, tm = t >> 7;
            int n0 = tn << 2;
            float4 w0v = *(const float4*)&s_wt[n0];
            float4 w1v = *(const float4*)&s_wt[kN + n0];
            #pragma unroll
            for (int r = 0; r < 4; ++r) {
                int m = tm + (r << 3);
                float er0 = s_er[m], er1 = s_er[kM + m];
                float ad0 = s_ad[m], ad1 = s_ad[kM + m];
                float4* mp = (float4*)&s_mem[m * kMLD + n0];
                float4 v = *mp;
                v.x = v.x * (1.0f - er0 * w0v.x) * (1.0f - er1 * w1v.x) + ad0 * w0v.x + ad1 * w1v.x;
                v.y = v.y * (1.0f - er0 * w0v.y) * (1.0f - er1 * w1v.y) + ad0 * w0v.y + ad1 * w1v.y;
                v.z = v.z * (1.0f - er0 * w0v.z) * (1.0f - er1 * w1v.z) + ad0 * w0v.z + ad1 * w1v.z;
                v.w = v.w * (1.0f - er0 * w0v.w) * (1.0f - er1 * w1v.w) + ad0 * w0v.w + ad1 * w1v.w;
                *mp = v;
            }
        }
        __syncthreads();

        // ---- P4: content scores beta * cos-sim (fused column norm) ----
        if (t < kN) {
            int n = t;
            float c0 = 0.0f, c1 = 0.0f, ss = 0.0f;
            #pragma unroll
            for (int m = 0; m < kM; ++m) {
                float v = s_mem[m * kMLD + n];
                c0 = fmaf(s_kk[m], v, c0);
                c1 = fmaf(s_kk[kM + m], v, c1);
                ss = fmaf(v, v, ss);
            }
            float invc = 1.0f / (sqrtf(ss) + kEPS);
            s_tmp[n]      = s_beta[0] * (c0 * s_ikn[0] * invc);
            s_tmp[kN + n] = s_beta[1] * (c1 * s_ikn[1] * invc);
        }
        __syncthreads();

        // ---- P5: softmax (no max-sub) + gate -> wt_c, single barrier ----
        {
            int h = t >> 9;
            float e = __expf(s_tmp[t]);
            float sm = e;
            sm += __shfl_xor(sm, 1);
            sm += __shfl_xor(sm, 2);
            sm += __shfl_xor(sm, 4);
            sm += __shfl_xor(sm, 8);
            sm += __shfl_xor(sm, 16);
            sm += __shfl_xor(sm, 32);
            if (lane == 0) s_red[wid] = sm;
            __syncthreads();
            float tot = 0.0f;
            #pragma unroll
            for (int i = 0; i < 8; ++i) tot += s_red[h * 8 + i];
            float wc = s_g[h] * e / tot + (1.0f - s_g[h]) * s_wt[t];
            s_tmp[t] = wc;
        }
        __syncthreads();

        // ---- P6+P7: conv + sharpen + sum + normalize + bookmark + jump ----
        {
            int h = t >> 9, n = t & 511;
            const float* wcp = &s_tmp[h * kN];
            float cv = s_shift[h][0] * wcp[(n + 1) & 511]
                     + s_shift[h][1] * wcp[n]
                     + s_shift[h][2] * wcp[(n + 511) & 511];
            float wsh = exp2f(s_gam[h] * __log2f(cv + kEPS));
            float sm = wsh;
            sm += __shfl_xor(sm, 1);
            sm += __shfl_xor(sm, 2);
            sm += __shfl_xor(sm, 4);
            sm += __shfl_xor(sm, 8);
            sm += __shfl_xor(sm, 16);
            sm += __shfl_xor(sm, 32);
            if (lane == 0) s_red[wid] = sm;
            __syncthreads();
            float tot = 0.0f;
            #pragma unroll
            for (int i = 0; i < 8; ++i) tot += s_red[h * 8 + i];
            float wn = wsh / tot;
            float dold = s_wtd[t];
            s_wtd[t] = (1.0f - s_jd[h]) * dold + s_jd[h] * wn;
            float wa0 = (n == 0) ? 1.0f : 0.0f;
            s_wt[t] = s_jmp[h][0] * wn + s_jmp[h][1] * wa0 + s_jmp[h][2] * dold;
        }
        __syncthreads();
    }
}

extern "C" void kernel_launch(void* const* d_in, const int* in_sizes, int n_in,
                              void* d_out, int out_size, void* d_ws, size_t ws_size,
                              hipStream_t stream) {
    const float* x   = (const float*)d_in[0];
    const float* Ws  = (const float*)d_in[1];
    const float* bs  = (const float*)d_in[2];
    const float* Wo  = (const float*)d_in[3];
    const float* bo  = (const float*)d_in[4];
    const float* Wu  = (const float*)d_in[5];
    const float* bu  = (const float*)d_in[6];
    float* outp = (float*)d_out;

    float* xw = (float*)d_ws;
    unsigned int* Wb = (unsigned int*)((char*)d_ws + kWbOffBytes);

    prep_xw<<<dim3(kB * kS), dim3(640), 0, stream>>>(x, Ws, bs, Wo, bo, Wu, bu, xw);
    prep_pack<<<dim3((kRP * kNC + 1023) / 1024), dim3(1024), 0, stream>>>(Ws, Wo, Wu, Wb);
    dwm_kernel<<<dim3(kB), dim3(NTHREADS), 0, stream>>>(xw, Wb, outp);
}

// Round 8
// 1671.629 us; speedup vs baseline: 1.2142x; 1.2142x over previous
//
#include <hip/hip_runtime.h>
#include <math.h>

#define NTHREADS 1024

namespace {
constexpr int kB = 8, kS = 96, kIN = 128, kH = 2, kM = 32, kN = 512;
constexpr int kSTATE = 256, kOUT = 126, kUH = 106;
constexpr int kNC = 594;            // GEMV output columns (256+126+212)
constexpr int kRP = 160;            // row-pairs total
constexpr int kWBR = 32;            // read-part row-pairs cached in LDS
constexpr int kMLD = 524;           // padded mem row stride (16B-aligned, low-conflict)
constexpr float kEPS = 1e-12f;
constexpr int kXWfloats = kB * kS * kNC;
constexpr size_t kWbOffBytes = (size_t)kXWfloats * 4;
}

__device__ __forceinline__ float sigm_(float x) { return 1.0f / (1.0f + __expf(-x)); }
__device__ __forceinline__ float splus_(float x) { return x > 20.0f ? x : __logf(1.0f + __expf(x)); }
__device__ __forceinline__ float blo_(unsigned int u) { return __uint_as_float(u << 16); }
__device__ __forceinline__ float bhi_(unsigned int u) { return __uint_as_float(u & 0xffff0000u); }

// ---- prep A: xw[row][c] = bias[c] + sum_{i<128} x[row][i] * W[i][c] ----
__global__ __launch_bounds__(640) void prep_xw(
    const float* __restrict__ x,
    const float* __restrict__ Ws, const float* __restrict__ bs,
    const float* __restrict__ Wo, const float* __restrict__ bo,
    const float* __restrict__ Wu, const float* __restrict__ bu,
    float* __restrict__ xw)
{
    __shared__ float sx[kIN];
    const int row = blockIdx.x;
    const int t = threadIdx.x;
    if (t < kIN) sx[t] = x[row * kIN + t];
    __syncthreads();
    if (t < kNC) {
        const float* Wp; int ld, j; float acc;
        if (t < 256)      { Wp = Ws; ld = kSTATE;   j = t;       acc = bs[j]; }
        else if (t < 382) { Wp = Wo; ld = kOUT;     j = t - 256; acc = bo[j]; }
        else              { Wp = Wu; ld = kH * kUH; j = t - 382; acc = bu[j]; }
        const float* p = Wp + j;
        #pragma unroll 8
        for (int i = 0; i < kIN; ++i) acc = fmaf(sx[i], p[i * ld], acc);
        xw[row * kNC + t] = acc;
    }
}

__device__ __forceinline__ unsigned short rtn_bf16_(float v) {
    unsigned int bits = __float_as_uint(v);
    return (unsigned short)((bits + 0x7fffu + ((bits >> 16) & 1u)) >> 16);
}

// ---- prep B: Wb[r][c] = pack(bf16(w[2r][c]), bf16(w[2r+1][c])) over recurrent rows ----
__global__ __launch_bounds__(1024) void prep_pack(
    const float* __restrict__ Ws, const float* __restrict__ Wo,
    const float* __restrict__ Wu, unsigned int* __restrict__ Wb)
{
    int idx = blockIdx.x * 1024 + threadIdx.x;
    if (idx >= kRP * kNC) return;
    int r = idx / kNC, c = idx - r * kNC;
    auto fetch = [&](int i) -> float {
        int row = kIN + i;
        if (c < 256)      return Ws[row * kSTATE + c];
        else if (c < 382) return Wo[row * kOUT + (c - 256)];
        else              return Wu[row * (kH * kUH) + (c - 382)];
    };
    unsigned int lo = rtn_bf16_(fetch(2 * r));
    unsigned int hi = rtn_bf16_(fetch(2 * r + 1));
    Wb[idx] = (hi << 16) | lo;
}

__global__ __launch_bounds__(NTHREADS) void dwm_kernel(
    const float* __restrict__ xw,
    const unsigned int* __restrict__ Wb,   // [160][594] row-pair packed bf16
    float* __restrict__ out)
{
    __shared__ float s_mem[kM * kMLD];       // 67 KB memory [M][N] (padded)
    __shared__ unsigned int s_wbr[kWBR * kNC]; // 76 KB read-part weights
    __shared__ float s_wt[kH * kN];
    __shared__ float s_wtd[kH * kN];
    __shared__ float s_tmp[kH * kN];
    __shared__ float s_comb[320];            // [read(64) | state(256)]
    __shared__ float s_upd[kH * kUH];
    __shared__ float s_er[kH * kM], s_ad[kH * kM], s_kk[kH * kM];
    __shared__ float s_red[16];
    __shared__ float s_shift[kH][3], s_jmp[kH][3];
    __shared__ float s_jd[kH], s_gam[kH], s_beta[kH], s_g[kH], s_ikn[kH];

    const int b = blockIdx.x;
    const int t = threadIdx.x;
    const int wid = t >> 6;
    const int lane = t & 63;

    // ---- init: cache read-part weights in LDS; initial carry ----
    for (int i = t; i < kWBR * kNC; i += NTHREADS) s_wbr[i] = Wb[i];
    for (int i = t; i < kM * kN; i += NTHREADS)
        s_mem[(i >> 9) * kMLD + (i & 511)] = 0.01f;
    for (int i = t; i < kH * kN; i += NTHREADS) {
        float v = ((i & 511) == 0) ? 1.0f : 0.0f;
        s_wt[i] = v; s_wtd[i] = v;
    }
    if (t < kSTATE) s_comb[64 + t] = 1.0f;   // state0 = 1
    __syncthreads();

    for (int step = 0; step < kS; ++step) {
        // ==== SPEC PHASE: [waves 12-15: P0 read-attention] ∥ [waves 0-9: GEMV state-part] ====
        float acc = 0.0f;
        if (t >= 768) {
            int tt = t - 768;
            int g = tt >> 2, l4 = tt & 3, h = g >> 5, m = g & 31;
            const float4* w4 = (const float4*)&s_wt[h * kN];
            const float4* m4 = (const float4*)&s_mem[m * kMLD];
            float ax = 0.0f, ay = 0.0f, az = 0.0f, aw = 0.0f;
            #pragma unroll
            for (int k = 0; k < 32; ++k) {
                float4 w = w4[l4 + 4 * k];
                float4 mv = m4[l4 + 4 * k];
                ax = fmaf(w.x, mv.x, ax); ay = fmaf(w.y, mv.y, ay);
                az = fmaf(w.z, mv.z, az); aw = fmaf(w.w, mv.w, aw);
            }
            float r = (ax + ay) + (az + aw);
            r += __shfl_xor(r, 1);
            r += __shfl_xor(r, 2);
            if (l4 == 0) s_comb[g] = r;
        } else if (t < kNC) {
            acc = xw[(b * kS + step) * kNC + t];
            const unsigned int* wps = Wb + kWBR * kNC + t;   // pairs 32..159
            #pragma unroll 16
            for (int r = 0; r < kRP - kWBR; ++r) {
                unsigned int u = wps[r * kNC];
                float2 cc = *(const float2*)&s_comb[64 + 2 * r];  // state slots
                acc = fmaf(blo_(u), cc.x, acc);
                acc = fmaf(bhi_(u), cc.y, acc);
            }
        }
        __syncthreads();

        // ==== TAIL (read-part from LDS) + P1b dispatch ====
        if (t < kNC) {
            #pragma unroll 8
            for (int r = 0; r < kWBR; ++r) {
                unsigned int u = s_wbr[r * kNC + t];
                float2 cc = *(const float2*)&s_comb[2 * r];       // read slots
                acc = fmaf(blo_(u), cc.x, acc);
                acc = fmaf(bhi_(u), cc.y, acc);
            }
            if (t < kSTATE) {
                s_comb[64 + t] = sigm_(acc);
            } else if (t < kSTATE + kOUT) {
                out[(b * kS + step) * kOUT + (t - kSTATE)] = acc;
            } else {
                int idx = t - 382;
                int h = idx >= kUH;
                int j = idx - (h ? kUH : 0);
                if (j >= 8 && j < 40)        s_er[h * kM + j - 8]  = sigm_(acc);
                else if (j >= 40 && j < 72)  s_ad[h * kM + j - 40] = acc;
                else if (j >= 72 && j < 104) s_kk[h * kM + j - 72] = tanhf(acc);
                else s_upd[idx] = acc;
            }
        }
        __syncthreads();

        // ---- P2 (t<66) + P3 (all threads) merged ----
        if (t < 64) {
            int h = t >> 5, m = t & 31;
            float kv = s_kk[t];
            float ss = kv * kv;
            ss += __shfl_xor(ss, 1);
            ss += __shfl_xor(ss, 2);
            ss += __shfl_xor(ss, 4);
            ss += __shfl_xor(ss, 8);
            ss += __shfl_xor(ss, 16);
            if (m == 0) s_ikn[h] = 1.0f / (sqrtf(ss) + kEPS);
        } else if (t == 64 || t == 65) {
            int h = t - 64;
            const float* u = &s_upd[h * kUH];
            float b0 = splus_(u[0]), b1 = splus_(u[1]), b2 = splus_(u[2]);
            float mx = fmaxf(b0, fmaxf(b1, b2));
            float e0 = __expf(b0 - mx), e1 = __expf(b1 - mx), e2 = __expf(b2 - mx);
            float inv = 1.0f / (e0 + e1 + e2);
            s_shift[h][0] = e0 * inv; s_shift[h][1] = e1 * inv; s_shift[h][2] = e2 * inv;
            s_jd[h] = sigm_(u[3]);
            b0 = u[4]; b1 = u[5]; b2 = u[6];
            mx = fmaxf(b0, fmaxf(b1, b2));
            e0 = __expf(b0 - mx); e1 = __expf(b1 - mx); e2 = __expf(b2 - mx);
            inv = 1.0f / (e0 + e1 + e2);
            s_jmp[h][0] = e0 * inv; s_jmp[h][1] = e1 * inv; s_jmp[h][2] = e2 * inv;
            s_gam[h]  = 1.0f + splus_(u[7]);
            s_beta[h] = splus_(u[104]);
            s_g[h]    = sigm_(u[105]);
        }
        // P3: erase+add, float4, wt hoisted (uses OLD s_wt)
        {
            int tn = t & 127, tm = t >> 7;
            int n0 = tn << 2;
            float4 w0v = *(const float4*)&s_wt[n0];
            float4 w1v = *(const float4*)&s_wt[kN + n0];
            #pragma unroll
            for (int r = 0; r < 4; ++r) {
                int m = tm + (r << 3);
                float er0 = s_er[m], er1 = s_er[kM + m];
                float ad0 = s_ad[m], ad1 = s_ad[kM + m];
                float4* mp = (float4*)&s_mem[m * kMLD + n0];
                float4 v = *mp;
                v.x = v.x * (1.0f - er0 * w0v.x) * (1.0f - er1 * w1v.x) + ad0 * w0v.x + ad1 * w1v.x;
                v.y = v.y * (1.0f - er0 * w0v.y) * (1.0f - er1 * w1v.y) + ad0 * w0v.y + ad1 * w1v.y;
                v.z = v.z * (1.0f - er0 * w0v.z) * (1.0f - er1 * w1v.z) + ad0 * w0v.z + ad1 * w1v.z;
                v.w = v.w * (1.0f - er0 * w0v.w) * (1.0f - er1 * w1v.w) + ad0 * w0v.w + ad1 * w1v.w;
                *mp = v;
            }
        }
        __syncthreads();

        // ---- P4: content scores beta * cos-sim (fused column norm) ----
        if (t < kN) {
            int n = t;
            float c0 = 0.0f, c1 = 0.0f, ss = 0.0f;
            #pragma unroll
            for (int m = 0; m < kM; ++m) {
                float v = s_mem[m * kMLD + n];
                c0 = fmaf(s_kk[m], v, c0);
                c1 = fmaf(s_kk[kM + m], v, c1);
                ss = fmaf(v, v, ss);
            }
            float invc = 1.0f / (sqrtf(ss) + kEPS);
            s_tmp[n]      = s_beta[0] * (c0 * s_ikn[0] * invc);
            s_tmp[kN + n] = s_beta[1] * (c1 * s_ikn[1] * invc);
        }
        __syncthreads();

        // ---- P5: softmax (no max-sub) + gate -> wt_c ----
        {
            int h = t >> 9;
            float e = __expf(s_tmp[t]);
            float sm = e;
            sm += __shfl_xor(sm, 1);
            sm += __shfl_xor(sm, 2);
            sm += __shfl_xor(sm, 4);
            sm += __shfl_xor(sm, 8);
            sm += __shfl_xor(sm, 16);
            sm += __shfl_xor(sm, 32);
            if (lane == 0) s_red[wid] = sm;
            __syncthreads();
            float tot = 0.0f;
            #pragma unroll
            for (int i = 0; i < 8; ++i) tot += s_red[h * 8 + i];
            float wc = s_g[h] * e / tot + (1.0f - s_g[h]) * s_wt[t];
            s_tmp[t] = wc;
        }
        __syncthreads();

        // ---- P6+P7: conv + sharpen + sum + normalize + bookmark + jump ----
        {
            int h = t >> 9, n = t & 511;
            const float* wcp = &s_tmp[h * kN];
            float cv = s_shift[h][0] * wcp[(n + 1) & 511]
                     + s_shift[h][1] * wcp[n]
                     + s_shift[h][2] * wcp[(n + 511) & 511];
            float wsh = exp2f(s_gam[h] * __log2f(cv + kEPS));
            float sm = wsh;
            sm += __shfl_xor(sm, 1);
            sm += __shfl_xor(sm, 2);
            sm += __shfl_xor(sm, 4);
            sm += __shfl_xor(sm, 8);
            sm += __shfl_xor(sm, 16);
            sm += __shfl_xor(sm, 32);
            if (lane == 0) s_red[wid] = sm;
            __syncthreads();
            float tot = 0.0f;
            #pragma unroll
            for (int i = 0; i < 8; ++i) tot += s_red[h * 8 + i];
            float wn = wsh / tot;
            float dold = s_wtd[t];
            s_wtd[t] = (1.0f - s_jd[h]) * dold + s_jd[h] * wn;
            float wa0 = (n == 0) ? 1.0f : 0.0f;
            s_wt[t] = s_jmp[h][0] * wn + s_jmp[h][1] * wa0 + s_jmp[h][2] * dold;
        }
        __syncthreads();
    }
}

extern "C" void kernel_launch(void* const* d_in, const int* in_sizes, int n_in,
                              void* d_out, int out_size, void* d_ws, size_t ws_size,
                              hipStream_t stream) {
    const float* x   = (const float*)d_in[0];
    const float* Ws  = (const float*)d_in[1];
    const float* bs  = (const float*)d_in[2];
    const float* Wo  = (const float*)d_in[3];
    const float* bo  = (const float*)d_in[4];
    const float* Wu  = (const float*)d_in[5];
    const float* bu  = (const float*)d_in[6];
    float* outp = (float*)d_out;

    float* xw = (float*)d_ws;
    unsigned int* Wb = (unsigned int*)((char*)d_ws + kWbOffBytes);

    prep_xw<<<dim3(kB * kS), dim3(640), 0, stream>>>(x, Ws, bs, Wo, bo, Wu, bu, xw);
    prep_pack<<<dim3((kRP * kNC + 1023) / 1024), dim3(1024), 0, stream>>>(Ws, Wo, Wu, Wb);
    dwm_kernel<<<dim3(kB), dim3(NTHREADS), 0, stream>>>(xw, Wb, outp);
}

// Round 9
// 1645.019 us; speedup vs baseline: 1.2339x; 1.0162x over previous
//
#include <hip/hip_runtime.h>
#include <math.h>

#define NTHREADS 1024

namespace {
constexpr int kB = 8, kS = 96, kIN = 128, kH = 2, kM = 32, kN = 512;
constexpr int kSTATE = 256, kOUT = 126, kUH = 106;
constexpr int kNC = 594;            // GEMV output columns (256+126+212)
constexpr int kRP = 160;            // row-pairs total (320 recurrent rows)
constexpr int kWBR = 32;            // read-part row-pairs cached in LDS
constexpr int kMLD = 520;           // padded mem row stride (R6-proven)
constexpr float kEPS = 1e-12f;
constexpr int kXWfloats = kB * kS * kNC;
constexpr size_t kWbOffBytes = (size_t)kXWfloats * 4;
}

__device__ __forceinline__ float sigm_(float x) { return 1.0f / (1.0f + __expf(-x)); }
__device__ __forceinline__ float splus_(float x) { return x > 20.0f ? x : __logf(1.0f + __expf(x)); }
__device__ __forceinline__ float blo_(unsigned int u) { return __uint_as_float(u << 16); }
__device__ __forceinline__ float bhi_(unsigned int u) { return __uint_as_float(u & 0xffff0000u); }

// ---- prep A: xw[row][c] = bias[c] + sum_{i<128} x[row][i] * W[i][c] ----
__global__ __launch_bounds__(640) void prep_xw(
    const float* __restrict__ x,
    const float* __restrict__ Ws, const float* __restrict__ bs,
    const float* __restrict__ Wo, const float* __restrict__ bo,
    const float* __restrict__ Wu, const float* __restrict__ bu,
    float* __restrict__ xw)
{
    __shared__ float sx[kIN];
    const int row = blockIdx.x;
    const int t = threadIdx.x;
    if (t < kIN) sx[t] = x[row * kIN + t];
    __syncthreads();
    if (t < kNC) {
        const float* Wp; int ld, j; float acc;
        if (t < 256)      { Wp = Ws; ld = kSTATE;   j = t;       acc = bs[j]; }
        else if (t < 382) { Wp = Wo; ld = kOUT;     j = t - 256; acc = bo[j]; }
        else              { Wp = Wu; ld = kH * kUH; j = t - 382; acc = bu[j]; }
        const float* p = Wp + j;
        #pragma unroll 8
        for (int i = 0; i < kIN; ++i) acc = fmaf(sx[i], p[i * ld], acc);
        xw[row * kNC + t] = acc;
    }
}

__device__ __forceinline__ unsigned short rtn_bf16_(float v) {
    unsigned int bits = __float_as_uint(v);
    return (unsigned short)((bits + 0x7fffu + ((bits >> 16) & 1u)) >> 16);
}

// ---- prep B: Wb[r][c] = pack(bf16(w[2r][c]), bf16(w[2r+1][c])) over recurrent rows ----
__global__ __launch_bounds__(1024) void prep_pack(
    const float* __restrict__ Ws, const float* __restrict__ Wo,
    const float* __restrict__ Wu, unsigned int* __restrict__ Wb)
{
    int idx = blockIdx.x * 1024 + threadIdx.x;
    if (idx >= kRP * kNC) return;
    int r = idx / kNC, c = idx - r * kNC;
    auto fetch = [&](int i) -> float {
        int row = kIN + i;
        if (c < 256)      return Ws[row * kSTATE + c];
        else if (c < 382) return Wo[row * kOUT + (c - 256)];
        else              return Wu[row * (kH * kUH) + (c - 382)];
    };
    unsigned int lo = rtn_bf16_(fetch(2 * r));
    unsigned int hi = rtn_bf16_(fetch(2 * r + 1));
    Wb[idx] = (hi << 16) | lo;
}

__global__ __launch_bounds__(NTHREADS) void dwm_kernel(
    const float* __restrict__ xw,
    const unsigned int* __restrict__ Wb,   // [160][594] row-pair packed bf16
    float* __restrict__ out)
{
    __shared__ float s_mem[kM * kMLD];         // 66.6 KB memory [M][N] (padded)
    __shared__ unsigned int s_wbr[kWBR * kNC]; // 76 KB read-part weights
    __shared__ float s_wt[kH * kN];
    __shared__ float s_wtd[kH * kN];
    __shared__ float s_tmp[kH * kN];
    __shared__ float s_comb[320];              // [read(64) | state(256)]
    __shared__ float s_upd[kH * kUH];
    __shared__ float s_er[kH * kM], s_ad[kH * kM], s_kk[kH * kM];
    __shared__ float s_red[16];
    __shared__ float s_shift[kH][3], s_jmp[kH][3];
    __shared__ float s_jd[kH], s_gam[kH], s_beta[kH], s_g[kH], s_ikn[kH];

    const int b = blockIdx.x;
    const int t = threadIdx.x;
    const int wid = t >> 6;
    const int lane = t & 63;

    // ---- init: cache read-part weights in LDS; initial carry ----
    for (int i = t; i < kWBR * kNC; i += NTHREADS) s_wbr[i] = Wb[i];
    for (int i = t; i < kM * kN; i += NTHREADS)
        s_mem[(i >> 9) * kMLD + (i & 511)] = 0.01f;
    for (int i = t; i < kH * kN; i += NTHREADS) {
        float v = ((i & 511) == 0) ? 1.0f : 0.0f;
        s_wt[i] = v; s_wtd[i] = v;
    }
    if (t < kSTATE) s_comb[64 + t] = 1.0f;   // state0 = 1
    __syncthreads();

    for (int step = 0; step < kS; ++step) {
        // ---- P0: read[h,m] = sum_n wt[h,n]*mem[m,n] via float4 (16 waves, 8-deep) ----
        {
            int g = t >> 4, l16 = t & 15, h = g >> 5, m = g & 31;
            const float4* w4 = (const float4*)&s_wt[h * kN];
            const float4* m4 = (const float4*)&s_mem[m * kMLD];
            float ax = 0.0f, ay = 0.0f, az = 0.0f, aw = 0.0f;
            #pragma unroll
            for (int k = 0; k < 8; ++k) {
                float4 w = w4[l16 + 16 * k];
                float4 mv = m4[l16 + 16 * k];
                ax = fmaf(w.x, mv.x, ax); ay = fmaf(w.y, mv.y, ay);
                az = fmaf(w.z, mv.z, az); aw = fmaf(w.w, mv.w, aw);
            }
            float acc = (ax + ay) + (az + aw);
            acc += __shfl_xor(acc, 1);
            acc += __shfl_xor(acc, 2);
            acc += __shfl_xor(acc, 4);
            acc += __shfl_xor(acc, 8);
            if (l16 == 0) s_comb[g] = acc;
        }
        __syncthreads();

        // ---- P1a: GEMV — thread t owns column t; LDS read-part + streamed state-part ----
        float acc = 0.0f;
        if (t < kNC) {
            float accg = xw[(b * kS + step) * kNC + t];
            const unsigned int* wps = Wb + kWBR * kNC + t;   // row-pairs 32..159
            float accl = 0.0f;
            #pragma unroll 8
            for (int r = 0; r < kWBR; ++r) {
                unsigned int u = s_wbr[r * kNC + t];
                float2 cc = *(const float2*)&s_comb[2 * r];       // read slots
                accl = fmaf(blo_(u), cc.x, accl);
                accl = fmaf(bhi_(u), cc.y, accl);
            }
            #pragma unroll 16
            for (int r = 0; r < kRP - kWBR; ++r) {
                unsigned int u = wps[r * kNC];
                float2 cc = *(const float2*)&s_comb[64 + 2 * r];  // state slots
                accg = fmaf(blo_(u), cc.x, accg);
                accg = fmaf(bhi_(u), cc.y, accg);
            }
            acc = accl + accg;
        }
        __syncthreads();   // all s_comb reads done before state overwrite

        // ---- P1b: dispatch (activations fused) ----
        if (t < kNC) {
            if (t < kSTATE) {
                s_comb[64 + t] = sigm_(acc);
            } else if (t < kSTATE + kOUT) {
                out[(b * kS + step) * kOUT + (t - kSTATE)] = acc;
            } else {
                int idx = t - 382;
                int h = idx >= kUH;
                int j = idx - (h ? kUH : 0);
                if (j >= 8 && j < 40)        s_er[h * kM + j - 8]  = sigm_(acc);
                else if (j >= 40 && j < 72)  s_ad[h * kM + j - 40] = acc;
                else if (j >= 72 && j < 104) s_kk[h * kM + j - 72] = tanhf(acc);
                else s_upd[idx] = acc;
            }
        }
        __syncthreads();

        // ---- P2 (t<66) + P3 (all threads) merged ----
        if (t < 64) {
            int h = t >> 5, m = t & 31;
            float kv = s_kk[t];
            float ss = kv * kv;
            ss += __shfl_xor(ss, 1);
            ss += __shfl_xor(ss, 2);
            ss += __shfl_xor(ss, 4);
            ss += __shfl_xor(ss, 8);
            ss += __shfl_xor(ss, 16);
            if (m == 0) s_ikn[h] = 1.0f / (sqrtf(ss) + kEPS);
        } else if (t == 64 || t == 65) {
            int h = t - 64;
            const float* u = &s_upd[h * kUH];
            float b0 = splus_(u[0]), b1 = splus_(u[1]), b2 = splus_(u[2]);
            float mx = fmaxf(b0, fmaxf(b1, b2));
            float e0 = __expf(b0 - mx), e1 = __expf(b1 - mx), e2 = __expf(b2 - mx);
            float inv = 1.0f / (e0 + e1 + e2);
            s_shift[h][0] = e0 * inv; s_shift[h][1] = e1 * inv; s_shift[h][2] = e2 * inv;
            s_jd[h] = sigm_(u[3]);
            b0 = u[4]; b1 = u[5]; b2 = u[6];
            mx = fmaxf(b0, fmaxf(b1, b2));
            e0 = __expf(b0 - mx); e1 = __expf(b1 - mx); e2 = __expf(b2 - mx);
            inv = 1.0f / (e0 + e1 + e2);
            s_jmp[h][0] = e0 * inv; s_jmp[h][1] = e1 * inv; s_jmp[h][2] = e2 * inv;
            s_gam[h]  = 1.0f + splus_(u[7]);
            s_beta[h] = splus_(u[104]);
            s_g[h]    = sigm_(u[105]);
        }
        // P3: erase+add, float4, wt hoisted (uses OLD s_wt)
        {
            int tn = t & 127, tm = t >> 7;
            int n0 = tn << 2;
            float4 w0v = *(const float4*)&s_wt[n0];
            float4 w1v = *(const float4*)&s_wt[kN + n0];
            #pragma unroll
            for (int r = 0; r < 4; ++r) {
                int m = tm + (r << 3);
                float er0 = s_er[m], er1 = s_er[kM + m];
                float ad0 = s_ad[m], ad1 = s_ad[kM + m];
                float4* mp = (float4*)&s_mem[m * kMLD + n0];
                float4 v = *mp;
                v.x = v.x * (1.0f - er0 * w0v.x) * (1.0f - er1 * w1v.x) + ad0 * w0v.x + ad1 * w1v.x;
                v.y = v.y * (1.0f - er0 * w0v.y) * (1.0f - er1 * w1v.y) + ad0 * w0v.y + ad1 * w1v.y;
                v.z = v.z * (1.0f - er0 * w0v.z) * (1.0f - er1 * w1v.z) + ad0 * w0v.z + ad1 * w1v.z;
                v.w = v.w * (1.0f - er0 * w0v.w) * (1.0f - er1 * w1v.w) + ad0 * w0v.w + ad1 * w1v.w;
                *mp = v;
            }
        }
        __syncthreads();

        // ---- P4: content scores beta * cos-sim (fused column norm) ----
        if (t < kN) {
            int n = t;
            float c0 = 0.0f, c1 = 0.0f, ss = 0.0f;
            #pragma unroll
            for (int m = 0; m < kM; ++m) {
                float v = s_mem[m * kMLD + n];
                c0 = fmaf(s_kk[m], v, c0);
                c1 = fmaf(s_kk[kM + m], v, c1);
                ss = fmaf(v, v, ss);
            }
            float invc = 1.0f / (sqrtf(ss) + kEPS);
            s_tmp[n]      = s_beta[0] * (c0 * s_ikn[0] * invc);
            s_tmp[kN + n] = s_beta[1] * (c1 * s_ikn[1] * invc);
        }
        __syncthreads();

        // ---- P5: softmax (no max-sub) + gate -> wt_c ----
        {
            int h = t >> 9;
            float e = __expf(s_tmp[t]);
            float sm = e;
            sm += __shfl_xor(sm, 1);
            sm += __shfl_xor(sm, 2);
            sm += __shfl_xor(sm, 4);
            sm += __shfl_xor(sm, 8);
            sm += __shfl_xor(sm, 16);
            sm += __shfl_xor(sm, 32);
            if (lane == 0) s_red[wid] = sm;
            __syncthreads();
            float tot = 0.0f;
            #pragma unroll
            for (int i = 0; i < 8; ++i) tot += s_red[h * 8 + i];
            float wc = s_g[h] * e / tot + (1.0f - s_g[h]) * s_wt[t];
            s_tmp[t] = wc;
        }
        __syncthreads();

        // ---- P6+P7: conv + sharpen + sum + normalize + bookmark + jump ----
        {
            int h = t >> 9, n = t & 511;
            const float* wcp = &s_tmp[h * kN];
            float cv = s_shift[h][0] * wcp[(n + 1) & 511]
                     + s_shift[h][1] * wcp[n]
                     + s_shift[h][2] * wcp[(n + 511) & 511];
            float wsh = exp2f(s_gam[h] * __log2f(cv + kEPS));
            float sm = wsh;
            sm += __shfl_xor(sm, 1);
            sm += __shfl_xor(sm, 2);
            sm += __shfl_xor(sm, 4);
            sm += __shfl_xor(sm, 8);
            sm += __shfl_xor(sm, 16);
            sm += __shfl_xor(sm, 32);
            if (lane == 0) s_red[wid] = sm;
            __syncthreads();
            float tot = 0.0f;
            #pragma unroll
            for (int i = 0; i < 8; ++i) tot += s_red[h * 8 + i];
            float wn = wsh / tot;
            float dold = s_wtd[t];
            s_wtd[t] = (1.0f - s_jd[h]) * dold + s_jd[h] * wn;
            float wa0 = (n == 0) ? 1.0f : 0.0f;
            s_wt[t] = s_jmp[h][0] * wn + s_jmp[h][1] * wa0 + s_jmp[h][2] * dold;
        }
        __syncthreads();
    }
}

extern "C" void kernel_launch(void* const* d_in, const int* in_sizes, int n_in,
                              void* d_out, int out_size, void* d_ws, size_t ws_size,
                              hipStream_t stream) {
    const float* x   = (const float*)d_in[0];
    const float* Ws  = (const float*)d_in[1];
    const float* bs  = (const float*)d_in[2];
    const float* Wo  = (const float*)d_in[3];
    const float* bo  = (const float*)d_in[4];
    const float* Wu  = (const float*)d_in[5];
    const float* bu  = (const float*)d_in[6];
    float* outp = (float*)d_out;

    float* xw = (float*)d_ws;
    unsigned int* Wb = (unsigned int*)((char*)d_ws + kWbOffBytes);

    prep_xw<<<dim3(kB * kS), dim3(640), 0, stream>>>(x, Ws, bs, Wo, bo, Wu, bu, xw);
    prep_pack<<<dim3((kRP * kNC + 1023) / 1024), dim3(1024), 0, stream>>>(Ws, Wo, Wu, Wb);
    dwm_kernel<<<dim3(kB), dim3(NTHREADS), 0, stream>>>(xw, Wb, outp);
}

// Round 10
// 1009.889 us; speedup vs baseline: 2.0098x; 1.6289x over previous
//
#include <hip/hip_runtime.h>
#include <math.h>

#define NTHREADS 1024

namespace {
constexpr int kB = 8, kS = 96, kIN = 128, kH = 2, kM = 32, kN = 512;
constexpr int kSTATE = 256, kOUT = 126, kUH = 106;
constexpr int kNC = 594;            // GEMV output columns (256+126+212)
constexpr int kKR = 320;            // recurrent GEMV rows (read 64 + state 256)
constexpr int kMLD = 520;           // padded mem row stride (proven)
constexpr float kEPS = 1e-12f;
constexpr int kXWfloats = kB * kS * kNC;
constexpr size_t kWbOffBytes = (size_t)kXWfloats * 4;
}

__device__ __forceinline__ float sigm_(float x) { return 1.0f / (1.0f + __expf(-x)); }
__device__ __forceinline__ float splus_(float x) { return x > 20.0f ? x : __logf(1.0f + __expf(x)); }
__device__ __forceinline__ float blo_(unsigned int u) { return __uint_as_float(u << 16); }
__device__ __forceinline__ float bhi_(unsigned int u) { return __uint_as_float(u & 0xffff0000u); }

// ---- prep A: xw[row][c] = bias[c] + sum_{i<128} x[row][i] * W[i][c] ----
__global__ __launch_bounds__(640) void prep_xw(
    const float* __restrict__ x,
    const float* __restrict__ Ws, const float* __restrict__ bs,
    const float* __restrict__ Wo, const float* __restrict__ bo,
    const float* __restrict__ Wu, const float* __restrict__ bu,
    float* __restrict__ xw)
{
    __shared__ float sx[kIN];
    const int row = blockIdx.x;
    const int t = threadIdx.x;
    if (t < kIN) sx[t] = x[row * kIN + t];
    __syncthreads();
    if (t < kNC) {
        const float* Wp; int ld, j; float acc;
        if (t < 256)      { Wp = Ws; ld = kSTATE;   j = t;       acc = bs[j]; }
        else if (t < 382) { Wp = Wo; ld = kOUT;     j = t - 256; acc = bo[j]; }
        else              { Wp = Wu; ld = kH * kUH; j = t - 382; acc = bu[j]; }
        const float* p = Wp + j;
        #pragma unroll 8
        for (int i = 0; i < kIN; ++i) acc = fmaf(sx[i], p[i * ld], acc);
        xw[row * kNC + t] = acc;
    }
}

// ---- prep B: pack recurrent rows [128,448) into bf16 Wb[320][594] row-major (RTN-even) ----
__global__ __launch_bounds__(1024) void prep_pack(
    const float* __restrict__ Ws, const float* __restrict__ Wo,
    const float* __restrict__ Wu, unsigned short* __restrict__ Wb)
{
    int idx = blockIdx.x * 1024 + threadIdx.x;
    if (idx >= kKR * kNC) return;
    int i = idx / kNC, c = idx - i * kNC;
    float v;
    if (c < 256)      v = Ws[(kIN + i) * kSTATE + c];
    else if (c < 382) v = Wo[(kIN + i) * kOUT + (c - 256)];
    else              v = Wu[(kIN + i) * (kH * kUH) + (c - 382)];
    unsigned int bits = __float_as_uint(v);
    unsigned int r = (bits + 0x7fffu + ((bits >> 16) & 1u)) >> 16;
    Wb[idx] = (unsigned short)r;
}

__global__ __launch_bounds__(NTHREADS) void dwm_kernel(
    const float* __restrict__ xw,
    const unsigned int* __restrict__ Wb,   // [320][297] packed bf16 column pairs
    float* __restrict__ out)
{
    __shared__ float s_mem[kM * kMLD];     // 66.6 KB memory [M][N] (padded)
    __shared__ float s_wt[kH * kN];
    __shared__ float s_wtd[kH * kN];
    __shared__ float s_tmp[kH * kN];
    __shared__ float s_comb[320];          // [read(64) | state(256)]
    __shared__ float s_upd[kH * kUH];      // scalar interface params (raw)
    __shared__ float s_er[kH * kM], s_ad[kH * kM], s_kk[kH * kM];
    __shared__ float s_red[16];
    __shared__ float s_shift[kH][3], s_jmp[kH][3];
    __shared__ float s_jd[kH], s_gam[kH], s_beta[kH], s_g[kH], s_ikn[kH];

    const int b = blockIdx.x;
    const int t = threadIdx.x;
    const int wid = t >> 6;
    const int lane = t & 63;

    // ---- initial carry ----
    for (int i = t; i < kM * kN; i += NTHREADS)
        s_mem[(i >> 9) * kMLD + (i & 511)] = 0.01f;
    for (int i = t; i < kH * kN; i += NTHREADS) {
        float v = ((i & 511) == 0) ? 1.0f : 0.0f;
        s_wt[i] = v; s_wtd[i] = v;
    }
    if (t < kSTATE) s_comb[64 + t] = 1.0f;   // state0 = 1
    __syncthreads();

    for (int step = 0; step < kS; ++step) {
        // ---- P0: read[h,m] = sum_n wt[h,n]*mem[m,n] via float4 (16 waves) ----
        {
            int g = t >> 4, l16 = t & 15, h = g >> 5, m = g & 31;
            const float4* w4 = (const float4*)&s_wt[h * kN];
            const float4* m4 = (const float4*)&s_mem[m * kMLD];
            float ax = 0.0f, ay = 0.0f, az = 0.0f, aw = 0.0f;
            #pragma unroll
            for (int k = 0; k < 8; ++k) {
                float4 w = w4[l16 + 16 * k];
                float4 mv = m4[l16 + 16 * k];
                ax = fmaf(w.x, mv.x, ax); ay = fmaf(w.y, mv.y, ay);
                az = fmaf(w.z, mv.z, az); aw = fmaf(w.w, mv.w, aw);
            }
            float acc = (ax + ay) + (az + aw);
            acc += __shfl_xor(acc, 1);
            acc += __shfl_xor(acc, 2);
            acc += __shfl_xor(acc, 4);
            acc += __shfl_xor(acc, 8);
            if (l16 == 0) s_comb[g] = acc;
        }
        __syncthreads();

        // ---- P1a: GEMV — thread t owns columns (2t,2t+1); row-major u16, unroll 16 ----
        float a0 = 0.0f, a1 = 0.0f;
        if (t < 297) {
            const unsigned int* wp = Wb + t;
            const float* xr = &xw[(b * kS + step) * kNC + 2 * t];
            a0 = xr[0]; a1 = xr[1];
            #pragma unroll 16
            for (int i = 0; i < kKR; ++i) {
                unsigned int u = wp[i * 297];
                float c = s_comb[i];                 // broadcast LDS read
                a0 = fmaf(blo_(u), c, a0);
                a1 = fmaf(bhi_(u), c, a1);
            }
        }
        __syncthreads();   // all s_comb reads done before state overwrite

        // ---- P1b: dispatch (activations fused) ----
        if (t < 297) {
            int c0 = 2 * t;
            if (c0 < kSTATE) {
                s_comb[64 + c0] = sigm_(a0);         // next state -> comb slot
                s_comb[65 + c0] = sigm_(a1);
            } else if (c0 < kSTATE + kOUT) {
                float* o = &out[(b * kS + step) * kOUT];
                o[c0 - 256] = a0; o[c0 - 255] = a1;
            } else {
                int i0 = c0 - 382;
                auto disp = [&](int idx, float v) {
                    int h = idx >= kUH;
                    int j = idx - (h ? kUH : 0);
                    if (j >= 8 && j < 40)        s_er[h * kM + j - 8]  = sigm_(v);
                    else if (j >= 40 && j < 72)  s_ad[h * kM + j - 40] = v;
                    else if (j >= 72 && j < 104) s_kk[h * kM + j - 72] = tanhf(v);
                    else s_upd[idx] = v;
                };
                disp(i0, a0);
                disp(i0 + 1, a1);
            }
        }
        __syncthreads();

        // ---- P2 (t<66) + P3 (all threads) merged ----
        if (t < 64) {
            int h = t >> 5, m = t & 31;
            float kv = s_kk[t];
            float ss = kv * kv;
            ss += __shfl_xor(ss, 1);
            ss += __shfl_xor(ss, 2);
            ss += __shfl_xor(ss, 4);
            ss += __shfl_xor(ss, 8);
            ss += __shfl_xor(ss, 16);
            if (m == 0) s_ikn[h] = 1.0f / (sqrtf(ss) + kEPS);
        } else if (t == 64 || t == 65) {
            int h = t - 64;
            const float* u = &s_upd[h * kUH];
            float b0 = splus_(u[0]), b1 = splus_(u[1]), b2 = splus_(u[2]);
            float mx = fmaxf(b0, fmaxf(b1, b2));
            float e0 = __expf(b0 - mx), e1 = __expf(b1 - mx), e2 = __expf(b2 - mx);
            float inv = 1.0f / (e0 + e1 + e2);
            s_shift[h][0] = e0 * inv; s_shift[h][1] = e1 * inv; s_shift[h][2] = e2 * inv;
            s_jd[h] = sigm_(u[3]);
            b0 = u[4]; b1 = u[5]; b2 = u[6];
            mx = fmaxf(b0, fmaxf(b1, b2));
            e0 = __expf(b0 - mx); e1 = __expf(b1 - mx); e2 = __expf(b2 - mx);
            inv = 1.0f / (e0 + e1 + e2);
            s_jmp[h][0] = e0 * inv; s_jmp[h][1] = e1 * inv; s_jmp[h][2] = e2 * inv;
            s_gam[h]  = 1.0f + splus_(u[7]);
            s_beta[h] = splus_(u[104]);
            s_g[h]    = sigm_(u[105]);
        }
        // P3: erase+add, float4, wt hoisted (uses OLD s_wt)
        {
            int tn = t & 127, tm = t >> 7;
            int n0 = tn << 2;
            float4 w0v = *(const float4*)&s_wt[n0];
            float4 w1v = *(const float4*)&s_wt[kN + n0];
            #pragma unroll
            for (int r = 0; r < 4; ++r) {
                int m = tm + (r << 3);
                float er0 = s_er[m], er1 = s_er[kM + m];
                float ad0 = s_ad[m], ad1 = s_ad[kM + m];
                float4* mp = (float4*)&s_mem[m * kMLD + n0];
                float4 v = *mp;
                v.x = v.x * (1.0f - er0 * w0v.x) * (1.0f - er1 * w1v.x) + ad0 * w0v.x + ad1 * w1v.x;
                v.y = v.y * (1.0f - er0 * w0v.y) * (1.0f - er1 * w1v.y) + ad0 * w0v.y + ad1 * w1v.y;
                v.z = v.z * (1.0f - er0 * w0v.z) * (1.0f - er1 * w1v.z) + ad0 * w0v.z + ad1 * w1v.z;
                v.w = v.w * (1.0f - er0 * w0v.w) * (1.0f - er1 * w1v.w) + ad0 * w0v.w + ad1 * w1v.w;
                *mp = v;
            }
        }
        __syncthreads();

        // ---- P4: content scores + EXP + per-wave partial sums (fused) ----
        if (t < kN) {
            int n = t;
            float c0 = 0.0f, c1 = 0.0f, ss = 0.0f;
            #pragma unroll
            for (int m = 0; m < kM; ++m) {
                float v = s_mem[m * kMLD + n];
                c0 = fmaf(s_kk[m], v, c0);
                c1 = fmaf(s_kk[kM + m], v, c1);
                ss = fmaf(v, v, ss);
            }
            float invc = 1.0f / (sqrtf(ss) + kEPS);
            float e0 = __expf(s_beta[0] * (c0 * s_ikn[0] * invc));
            float e1 = __expf(s_beta[1] * (c1 * s_ikn[1] * invc));
            s_tmp[n]      = e0;
            s_tmp[kN + n] = e1;
            float sm0 = e0, sm1 = e1;
            sm0 += __shfl_xor(sm0, 1);  sm1 += __shfl_xor(sm1, 1);
            sm0 += __shfl_xor(sm0, 2);  sm1 += __shfl_xor(sm1, 2);
            sm0 += __shfl_xor(sm0, 4);  sm1 += __shfl_xor(sm1, 4);
            sm0 += __shfl_xor(sm0, 8);  sm1 += __shfl_xor(sm1, 8);
            sm0 += __shfl_xor(sm0, 16); sm1 += __shfl_xor(sm1, 16);
            sm0 += __shfl_xor(sm0, 32); sm1 += __shfl_xor(sm1, 32);
            if (lane == 0) { s_red[wid] = sm0; s_red[8 + wid] = sm1; }
        }
        __syncthreads();

        // ---- P5: gate -> wt_c (sums ready in s_red) ----
        {
            int h = t >> 9;
            float tot = 0.0f;
            #pragma unroll
            for (int i = 0; i < 8; ++i) tot += s_red[h * 8 + i];
            float e = s_tmp[t];
            float wc = s_g[h] * e / tot + (1.0f - s_g[h]) * s_wt[t];
            s_tmp[t] = wc;
        }
        __syncthreads();

        // ---- P6+P7: conv + sharpen + sum + normalize + bookmark + jump ----
        {
            int h = t >> 9, n = t & 511;
            const float* wcp = &s_tmp[h * kN];
            float cv = s_shift[h][0] * wcp[(n + 1) & 511]
                     + s_shift[h][1] * wcp[n]
                     + s_shift[h][2] * wcp[(n + 511) & 511];
            float wsh = exp2f(s_gam[h] * __log2f(cv + kEPS));
            float sm = wsh;
            sm += __shfl_xor(sm, 1);
            sm += __shfl_xor(sm, 2);
            sm += __shfl_xor(sm, 4);
            sm += __shfl_xor(sm, 8);
            sm += __shfl_xor(sm, 16);
            sm += __shfl_xor(sm, 32);
            if (lane == 0) s_red[wid] = sm;
            __syncthreads();
            float tot = 0.0f;
            #pragma unroll
            for (int i = 0; i < 8; ++i) tot += s_red[h * 8 + i];
            float wn = wsh / tot;
            float dold = s_wtd[t];
            s_wtd[t] = (1.0f - s_jd[h]) * dold + s_jd[h] * wn;
            float wa0 = (n == 0) ? 1.0f : 0.0f;
            s_wt[t] = s_jmp[h][0] * wn + s_jmp[h][1] * wa0 + s_jmp[h][2] * dold;
        }
        __syncthreads();
    }
}

extern "C" void kernel_launch(void* const* d_in, const int* in_sizes, int n_in,
                              void* d_out, int out_size, void* d_ws, size_t ws_size,
                              hipStream_t stream) {
    const float* x   = (const float*)d_in[0];
    const float* Ws  = (const float*)d_in[1];
    const float* bs  = (const float*)d_in[2];
    const float* Wo  = (const float*)d_in[3];
    const float* bo  = (const float*)d_in[4];
    const float* Wu  = (const float*)d_in[5];
    const float* bu  = (const float*)d_in[6];
    float* outp = (float*)d_out;

    float* xw = (float*)d_ws;
    unsigned short* Wb = (unsigned short*)((char*)d_ws + kWbOffBytes);

    prep_xw<<<dim3(kB * kS), dim3(640), 0, stream>>>(x, Ws, bs, Wo, bo, Wu, bu, xw);
    prep_pack<<<dim3((kKR * kNC + 1023) / 1024), dim3(1024), 0, stream>>>(Ws, Wo, Wu, Wb);
    dwm_kernel<<<dim3(kB), dim3(NTHREADS), 0, stream>>>(xw, (const unsigned int*)Wb, outp);
}